// Round 4
// baseline (678.323 us; speedup 1.0000x reference)
//
#include <hip/hip_runtime.h>
#include <hip/hip_bf16.h>
#include <stdint.h>

// Problem constants (fixed by setup_inputs)
#define M_TOT 8192
#define N_TOT 4096
#define K_TOT 4096
#define GROUP 128

// Tile config: 256x128 block tile (M-split x2 reuses dequanted Bt for 2x FLOPs),
// 4 waves (2x2), each wave 2 x (64x64) via 4x4 frags of 16x16x32, BK=64.
#define BM 256
#define BN 128
#define BK 64
#define BKP 72  // padded k-stride (+16B) -> fragment reads & staged writes conflict-free

// Round-2 lesson: fp16 reference arrays arrive as FLOAT32 ("else float*" rule).
// Round-3 lesson: Bt write pattern had 16-way bank conflicts (8.4e7 = 25% of cycles);
//   fixed by lane remap n = (tid&31) + 32*dn (bank = 4*lane, conflict-free).

using f32x4  = __attribute__((ext_vector_type(4))) float;
using bf16x8 = __attribute__((ext_vector_type(8))) __bf16;

__global__ __launch_bounds__(256, 2) void gptq_gemm(
    const float* __restrict__ x,       // [M, K] f32 (fp16-upcast)
    const int*   __restrict__ qweight, // [K/8, N]
    const int*   __restrict__ qzeros,  // [G, N/8]
    const float* __restrict__ scales,  // [G, N] f32
    const int*   __restrict__ g_idx,   // [K]
    const float* __restrict__ bias,    // [N] f32
    float* __restrict__ out)           // [M, N] f32
{
    __shared__ __align__(16) unsigned short As[BM * BKP];  // bf16 [256][72] = 36.9 KB
    __shared__ __align__(16) unsigned short Bt[BN * BKP];  // bf16 [128][72] = 18.4 KB

    const int tid  = threadIdx.x;
    const int wave = tid >> 6;
    const int lane = tid & 63;
    const int n0 = blockIdx.x * BN;
    const int m0 = blockIdx.y * BM;

    const int wm = (wave >> 1) * 64;   // wave row offset within 128-row half
    const int wn = (wave & 1) * 64;    // wave col offset

    const int l15  = lane & 15;
    const int quad = lane >> 4;        // 0..3

    f32x4 acc[2][4][4];
    #pragma unroll
    for (int mi = 0; mi < 2; ++mi)
        #pragma unroll
        for (int i = 0; i < 4; ++i)
            #pragma unroll
            for (int j = 0; j < 4; ++j)
                acc[mi][i][j] = (f32x4)0.f;

    // B staging lane map (conflict-free): thread -> 4 cols n = nb + 32*dn, k-subrow r
    const int nb  = tid & 31;          // column base 0..31
    const int r   = tid >> 5;          // 0..7 -> qweight sub-row (8 k's each)
    const int zsh = (nb & 7) * 4;      // nibble shift, same for all dn

    for (int kt = 0; kt < K_TOT / BK; ++kt) {
        const int k0 = kt * BK;

        // ---- stage A: 2048 chunks of 8 f32 -> bf16; 256 threads x 8 chunks ----
        #pragma unroll
        for (int i = 0; i < 8; ++i) {
            const int c   = tid + i * 256;
            const int row = c >> 3;
            const int cb  = (c & 7) << 3;
            const float* xp = x + (size_t)(m0 + row) * K_TOT + (k0 + cb);
            const float4 f0 = *(const float4*)xp;
            const float4 f1 = *(const float4*)(xp + 4);
            bf16x8 v;
            v[0] = (__bf16)f0.x; v[1] = (__bf16)f0.y;
            v[2] = (__bf16)f0.z; v[3] = (__bf16)f0.w;
            v[4] = (__bf16)f1.x; v[5] = (__bf16)f1.y;
            v[6] = (__bf16)f1.z; v[7] = (__bf16)f1.w;
            *(bf16x8*)&As[row * BKP + cb] = v;
        }

        // ---- stage B: dequant 4-bit -> bf16 (BK=64 inside one group) ----
        const int g    = g_idx[k0];
        const int qrow = (k0 >> 3) + r;
        #pragma unroll
        for (int dn = 0; dn < 4; ++dn) {
            const int n  = nb + dn * 32;
            const int qi = qweight[(size_t)qrow * N_TOT + (n0 + n)];
            const int zi = qzeros[g * (N_TOT / 8) + ((n0 + n) >> 3)];
            const float s = scales[g * N_TOT + (n0 + n)];
            const float zs = (float)(((zi >> zsh) & 0xF) + 1) * s;
            bf16x8 v;
            #pragma unroll
            for (int j = 0; j < 8; ++j) {
                const float w = (float)((qi >> (4 * j)) & 0xF);
                v[j] = (__bf16)(w * s - zs);   // (w - z - 1) * s
            }
            *(bf16x8*)&Bt[n * BKP + r * 8] = v;
        }

        __syncthreads();

        // ---- compute: 2 k-steps of 32, 2 m-subtiles reuse bv ----
        #pragma unroll
        for (int ks = 0; ks < 2; ++ks) {
            bf16x8 bv[4];
            #pragma unroll
            for (int nt = 0; nt < 4; ++nt)
                bv[nt] = *(const bf16x8*)&Bt[(wn + nt * 16 + l15) * BKP + ks * 32 + quad * 8];
            #pragma unroll
            for (int mi = 0; mi < 2; ++mi) {
                bf16x8 av[4];
                #pragma unroll
                for (int mt = 0; mt < 4; ++mt)
                    av[mt] = *(const bf16x8*)&As[(mi * 128 + wm + mt * 16 + l15) * BKP + ks * 32 + quad * 8];
                #pragma unroll
                for (int mt = 0; mt < 4; ++mt)
                    #pragma unroll
                    for (int nt = 0; nt < 4; ++nt)
                        acc[mi][mt][nt] = __builtin_amdgcn_mfma_f32_16x16x32_bf16(
                            av[mt], bv[nt], acc[mi][mt][nt], 0, 0, 0);
            }
        }
        __syncthreads();
    }

    // ---- epilogue: C/D layout col=lane&15, row=quad*4+reg (m89/m91-verified) ----
    #pragma unroll
    for (int mi = 0; mi < 2; ++mi) {
        #pragma unroll
        for (int nt = 0; nt < 4; ++nt) {
            const int col = n0 + wn + nt * 16 + l15;
            const float bv = bias[col];
            #pragma unroll
            for (int mt = 0; mt < 4; ++mt) {
                const int rowb = m0 + mi * 128 + wm + mt * 16 + quad * 4;
                #pragma unroll
                for (int i = 0; i < 4; ++i) {
                    out[(size_t)(rowb + i) * N_TOT + col] = acc[mi][mt][nt][i] + bv;
                }
            }
        }
    }
}

extern "C" void kernel_launch(void* const* d_in, const int* in_sizes, int n_in,
                              void* d_out, int out_size, void* d_ws, size_t ws_size,
                              hipStream_t stream) {
    const float* x  = (const float*)d_in[0];
    const int*   qw = (const int*)d_in[1];
    const int*   qz = (const int*)d_in[2];
    const float* sc = (const float*)d_in[3];
    const int*   gi = (const int*)d_in[4];
    const float* bs = (const float*)d_in[5];
    float* out = (float*)d_out;

    dim3 grid(N_TOT / BN, M_TOT / BM);  // (32, 32)
    gptq_gemm<<<grid, dim3(256), 0, stream>>>(x, qw, qz, sc, gi, bs, out);
}

// Round 5
// 597.938 us; speedup vs baseline: 1.1344x; 1.1344x over previous
//
#include <hip/hip_runtime.h>
#include <hip/hip_bf16.h>
#include <stdint.h>

// Problem constants (fixed by setup_inputs)
#define M_TOT 8192
#define N_TOT 4096
#define K_TOT 4096
#define GROUP 128

// Round-2 lesson: fp16 reference arrays arrive as FLOAT32 ("else float*" rule).
// Round-4 lesson: fused kernel is barrier/latency-bound (all pipes <25%); x is
//   re-converted 32x and W re-dequanted 32x. Two-pass: dequant/cast once, then
//   the proven m97 global_load_lds GEMM structure (874 TF lineage).

using f32x4  = __attribute__((ext_vector_type(4))) float;
using bf16x8 = __attribute__((ext_vector_type(8))) __bf16;

typedef __attribute__((address_space(3))) void as3_void;
typedef const __attribute__((address_space(1))) void as1_void;

// ---------------- pass 1a: cast x f32 -> bf16 (one-shot) ----------------
__global__ __launch_bounds__(256) void cast_x(const float* __restrict__ x,
                                              __bf16* __restrict__ xb) {
    const size_t t = (size_t)blockIdx.x * 256 + threadIdx.x;
    const float4 f0 = *(const float4*)(x + t * 8);
    const float4 f1 = *(const float4*)(x + t * 8 + 4);
    bf16x8 v;
    v[0]=(__bf16)f0.x; v[1]=(__bf16)f0.y; v[2]=(__bf16)f0.z; v[3]=(__bf16)f0.w;
    v[4]=(__bf16)f1.x; v[5]=(__bf16)f1.y; v[6]=(__bf16)f1.z; v[7]=(__bf16)f1.w;
    *(bf16x8*)(xb + t * 8) = v;
}

// ------- pass 1b: dequant qweight -> Wt [N][K] bf16 (LDS transpose) -------
__global__ __launch_bounds__(256) void dequant_w(
    const int*   __restrict__ qweight,  // [K/8, N]
    const int*   __restrict__ qzeros,   // [G, N/8]
    const float* __restrict__ scales,   // [G, N]
    const int*   __restrict__ g_idx,    // [K]
    __bf16* __restrict__ Wt)            // [N, K]
{
    __shared__ __align__(16) unsigned short T[64 * 72];  // [64n][72k]
    const int k0  = blockIdx.x * 64;
    const int n0  = blockIdx.y * 64;
    const int g   = g_idx[k0];          // 64-k tile sits in one group (64 | 128)
    const int tid = threadIdx.x;

    #pragma unroll
    for (int i = 0; i < 2; ++i) {
        const int idx = tid + i * 256;  // 0..511
        const int r   = idx >> 6;       // 0..7  (8 k's each)
        const int n   = idx & 63;
        const int qi  = qweight[(size_t)((k0 >> 3) + r) * N_TOT + n0 + n];
        const int zi  = qzeros[g * (N_TOT / 8) + ((n0 + n) >> 3)];
        const float s = scales[g * N_TOT + n0 + n];
        const float zs = (float)(((zi >> ((n & 7) * 4)) & 0xF) + 1) * s;
        bf16x8 v;
        #pragma unroll
        for (int j = 0; j < 8; ++j)
            v[j] = (__bf16)((float)((qi >> (4 * j)) & 0xF) * s - zs);  // (w-z-1)*s
        *(bf16x8*)&T[n * 72 + r * 8] = v;
    }
    __syncthreads();

    const int n = tid >> 2;             // 0..63
    const int c = (tid & 3) * 16;       // 0,16,32,48
    const bf16x8 a = *(const bf16x8*)&T[n * 72 + c];
    const bf16x8 b = *(const bf16x8*)&T[n * 72 + c + 8];
    __bf16* dst = Wt + (size_t)(n0 + n) * K_TOT + k0 + c;
    *(bf16x8*)dst = a;
    *(bf16x8*)(dst + 8) = b;
}

// ---------------- pass 2: m97-structure bf16 GEMM (B^T) ----------------
#define BM 128
#define BN 128
#define BK 64

__global__ __launch_bounds__(256) void gemm_bt(
    const __bf16* __restrict__ xb,   // [M, K]
    const __bf16* __restrict__ Wt,   // [N, K]
    const float*  __restrict__ bias, // [N]
    float* __restrict__ out)         // [M, N]
{
    __shared__ __align__(16) unsigned short As[BM * BK];  // unpadded: DMA-contiguous
    __shared__ __align__(16) unsigned short Bs[BN * BK];

    const int tid  = threadIdx.x;
    const int wave = tid >> 6;
    const int lane = tid & 63;
    const int n0 = blockIdx.x * BN;
    const int m0 = blockIdx.y * BM;

    const int wm = (wave >> 1) * 64;
    const int wn = (wave & 1) * 64;
    const int l15  = lane & 15;
    const int quad = lane >> 4;

    f32x4 acc[4][4];
    #pragma unroll
    for (int i = 0; i < 4; ++i)
        #pragma unroll
        for (int j = 0; j < 4; ++j)
            acc[i][j] = (f32x4)0.f;

    for (int kt = 0; kt < K_TOT / BK; ++kt) {
        const int k0 = kt * BK;

        // DMA staging: 16 B/lane; LDS dst = wave-uniform base + lane*16
        #pragma unroll
        for (int i = 0; i < 4; ++i) {
            const int c = tid + i * 256;                 // chunk id (16 B each)
            const __bf16* ga = xb + (size_t)(m0 + (c >> 3)) * K_TOT + (k0 + ((c & 7) << 3));
            __builtin_amdgcn_global_load_lds((as1_void*)ga,
                (as3_void*)&As[(i * 256 + wave * 64) * 8], 16, 0, 0);
            const __bf16* gb = Wt + (size_t)(n0 + (c >> 3)) * K_TOT + (k0 + ((c & 7) << 3));
            __builtin_amdgcn_global_load_lds((as1_void*)gb,
                (as3_void*)&Bs[(i * 256 + wave * 64) * 8], 16, 0, 0);
        }
        __syncthreads();

        #pragma unroll
        for (int ks = 0; ks < 2; ++ks) {
            bf16x8 av[4], bv[4];
            #pragma unroll
            for (int mt = 0; mt < 4; ++mt)
                av[mt] = *(const bf16x8*)&As[(wm + mt * 16 + l15) * BK + ks * 32 + quad * 8];
            #pragma unroll
            for (int nt = 0; nt < 4; ++nt)
                bv[nt] = *(const bf16x8*)&Bs[(wn + nt * 16 + l15) * BK + ks * 32 + quad * 8];
            #pragma unroll
            for (int mt = 0; mt < 4; ++mt)
                #pragma unroll
                for (int nt = 0; nt < 4; ++nt)
                    acc[mt][nt] = __builtin_amdgcn_mfma_f32_16x16x32_bf16(
                        av[mt], bv[nt], acc[mt][nt], 0, 0, 0);
        }
        __syncthreads();
    }

    // epilogue: C/D layout col=lane&15, row=quad*4+reg (m89/m91-verified)
    #pragma unroll
    for (int nt = 0; nt < 4; ++nt) {
        const int col = n0 + wn + nt * 16 + l15;
        const float bv = bias[col];
        #pragma unroll
        for (int mt = 0; mt < 4; ++mt) {
            const int rowb = m0 + wm + mt * 16 + quad * 4;
            #pragma unroll
            for (int i = 0; i < 4; ++i)
                out[(size_t)(rowb + i) * N_TOT + col] = acc[mt][nt][i] + bv;
        }
    }
}

// ---------------- fallback: round-4 fused kernel (proven correct) ----------------
#define FBM 256
#define FBN 128
#define FBKP 72

__global__ __launch_bounds__(256, 2) void gptq_gemm_fused(
    const float* __restrict__ x, const int* __restrict__ qweight,
    const int* __restrict__ qzeros, const float* __restrict__ scales,
    const int* __restrict__ g_idx, const float* __restrict__ bias,
    float* __restrict__ out)
{
    __shared__ __align__(16) unsigned short As[FBM * FBKP];
    __shared__ __align__(16) unsigned short Bt[FBN * FBKP];

    const int tid  = threadIdx.x;
    const int wave = tid >> 6;
    const int lane = tid & 63;
    const int n0 = blockIdx.x * FBN;
    const int m0 = blockIdx.y * FBM;
    const int wm = (wave >> 1) * 64;
    const int wn = (wave & 1) * 64;
    const int l15  = lane & 15;
    const int quad = lane >> 4;

    f32x4 acc[2][4][4];
    #pragma unroll
    for (int mi = 0; mi < 2; ++mi)
        #pragma unroll
        for (int i = 0; i < 4; ++i)
            #pragma unroll
            for (int j = 0; j < 4; ++j)
                acc[mi][i][j] = (f32x4)0.f;

    const int nb  = tid & 31;
    const int r   = tid >> 5;
    const int zsh = (nb & 7) * 4;

    for (int kt = 0; kt < K_TOT / 64; ++kt) {
        const int k0 = kt * 64;
        #pragma unroll
        for (int i = 0; i < 8; ++i) {
            const int c   = tid + i * 256;
            const int row = c >> 3;
            const int cb  = (c & 7) << 3;
            const float* xp = x + (size_t)(m0 + row) * K_TOT + (k0 + cb);
            const float4 f0 = *(const float4*)xp;
            const float4 f1 = *(const float4*)(xp + 4);
            bf16x8 v;
            v[0]=(__bf16)f0.x; v[1]=(__bf16)f0.y; v[2]=(__bf16)f0.z; v[3]=(__bf16)f0.w;
            v[4]=(__bf16)f1.x; v[5]=(__bf16)f1.y; v[6]=(__bf16)f1.z; v[7]=(__bf16)f1.w;
            *(bf16x8*)&As[row * FBKP + cb] = v;
        }
        const int g    = g_idx[k0];
        const int qrow = (k0 >> 3) + r;
        #pragma unroll
        for (int dn = 0; dn < 4; ++dn) {
            const int n  = nb + dn * 32;
            const int qi = qweight[(size_t)qrow * N_TOT + (n0 + n)];
            const int zi = qzeros[g * (N_TOT / 8) + ((n0 + n) >> 3)];
            const float s = scales[g * N_TOT + (n0 + n)];
            const float zs = (float)(((zi >> zsh) & 0xF) + 1) * s;
            bf16x8 v;
            #pragma unroll
            for (int j = 0; j < 8; ++j)
                v[j] = (__bf16)((float)((qi >> (4 * j)) & 0xF) * s - zs);
            *(bf16x8*)&Bt[n * FBKP + r * 8] = v;
        }
        __syncthreads();
        #pragma unroll
        for (int ks = 0; ks < 2; ++ks) {
            bf16x8 bv[4];
            #pragma unroll
            for (int nt = 0; nt < 4; ++nt)
                bv[nt] = *(const bf16x8*)&Bt[(wn + nt * 16 + l15) * FBKP + ks * 32 + quad * 8];
            #pragma unroll
            for (int mi = 0; mi < 2; ++mi) {
                bf16x8 av[4];
                #pragma unroll
                for (int mt = 0; mt < 4; ++mt)
                    av[mt] = *(const bf16x8*)&As[(mi * 128 + wm + mt * 16 + l15) * FBKP + ks * 32 + quad * 8];
                #pragma unroll
                for (int mt = 0; mt < 4; ++mt)
                    #pragma unroll
                    for (int nt = 0; nt < 4; ++nt)
                        acc[mi][mt][nt] = __builtin_amdgcn_mfma_f32_16x16x32_bf16(
                            av[mt], bv[nt], acc[mi][mt][nt], 0, 0, 0);
            }
        }
        __syncthreads();
    }
    #pragma unroll
    for (int mi = 0; mi < 2; ++mi)
        #pragma unroll
        for (int nt = 0; nt < 4; ++nt) {
            const int col = n0 + wn + nt * 16 + l15;
            const float bv = bias[col];
            #pragma unroll
            for (int mt = 0; mt < 4; ++mt) {
                const int rowb = m0 + mi * 128 + wm + mt * 16 + quad * 4;
                #pragma unroll
                for (int i = 0; i < 4; ++i)
                    out[(size_t)(rowb + i) * N_TOT + col] = acc[mi][mt][nt][i] + bv;
            }
        }
}

extern "C" void kernel_launch(void* const* d_in, const int* in_sizes, int n_in,
                              void* d_out, int out_size, void* d_ws, size_t ws_size,
                              hipStream_t stream) {
    const float* x  = (const float*)d_in[0];
    const int*   qw = (const int*)d_in[1];
    const int*   qz = (const int*)d_in[2];
    const float* sc = (const float*)d_in[3];
    const int*   gi = (const int*)d_in[4];
    const float* bs = (const float*)d_in[5];
    float* out = (float*)d_out;

    const size_t xb_bytes = (size_t)M_TOT * K_TOT * 2;   // 67,108,864
    const size_t wt_bytes = (size_t)N_TOT * K_TOT * 2;   // 33,554,432

    if (ws_size >= xb_bytes + wt_bytes) {
        __bf16* xb = (__bf16*)d_ws;
        __bf16* Wt = (__bf16*)((char*)d_ws + xb_bytes);
        cast_x<<<dim3((M_TOT * K_TOT) / (256 * 8)), dim3(256), 0, stream>>>(x, xb);
        dequant_w<<<dim3(K_TOT / 64, N_TOT / 64), dim3(256), 0, stream>>>(qw, qz, sc, gi, Wt);
        gemm_bt<<<dim3(N_TOT / BN, M_TOT / BM), dim3(256), 0, stream>>>(xb, Wt, bs, out);
    } else {
        gptq_gemm_fused<<<dim3(N_TOT / FBN, M_TOT / FBM), dim3(256), 0, stream>>>(
            x, qw, qz, sc, gi, bs, out);
    }
}

// Round 6
// 526.393 us; speedup vs baseline: 1.2886x; 1.1359x over previous
//
#include <hip/hip_runtime.h>
#include <hip/hip_bf16.h>
#include <stdint.h>

// Problem constants (fixed by setup_inputs)
#define M_TOT 8192
#define N_TOT 4096
#define K_TOT 4096
#define GROUP 128

// Round-2 lesson: fp16 reference arrays arrive as FLOAT32 ("else float*" rule).
// Round-4 lesson: fused one-pass is barrier/latency-bound; two-pass wins.
// Round-5 lesson: unpadded [128][64] tiles -> 16-way bank conflicts on every
//   ds_read_b128 (1.0e8 conflict cycles = 40% of CU-cycles). Fix: XOR-swizzle
//   chunk placement on the GLOBAL side of global_load_lds (DMA dst stays
//   lane-contiguous); read side XORs (ks*4+quad) ^ (row&7) -> 2-way max (free).

using f32x4  = __attribute__((ext_vector_type(4))) float;
using bf16x8 = __attribute__((ext_vector_type(8))) __bf16;

typedef __attribute__((address_space(3))) void as3_void;
typedef const __attribute__((address_space(1))) void as1_void;

// ---------------- pass 1a: cast x f32 -> bf16 (one-shot) ----------------
__global__ __launch_bounds__(256) void cast_x(const float* __restrict__ x,
                                              __bf16* __restrict__ xb) {
    const size_t t = (size_t)blockIdx.x * 256 + threadIdx.x;
    const float4 f0 = *(const float4*)(x + t * 8);
    const float4 f1 = *(const float4*)(x + t * 8 + 4);
    bf16x8 v;
    v[0]=(__bf16)f0.x; v[1]=(__bf16)f0.y; v[2]=(__bf16)f0.z; v[3]=(__bf16)f0.w;
    v[4]=(__bf16)f1.x; v[5]=(__bf16)f1.y; v[6]=(__bf16)f1.z; v[7]=(__bf16)f1.w;
    *(bf16x8*)(xb + t * 8) = v;
}

// ------- pass 1b: dequant qweight -> Wt [N][K] bf16 (LDS transpose) -------
__global__ __launch_bounds__(256) void dequant_w(
    const int*   __restrict__ qweight,  // [K/8, N]
    const int*   __restrict__ qzeros,   // [G, N/8]
    const float* __restrict__ scales,   // [G, N]
    const int*   __restrict__ g_idx,    // [K]
    __bf16* __restrict__ Wt)            // [N, K]
{
    __shared__ __align__(16) unsigned short T[64 * 72];  // [64n][72k]
    const int k0  = blockIdx.x * 64;
    const int n0  = blockIdx.y * 64;
    const int g   = g_idx[k0];          // 64-k tile sits in one group (64 | 128)
    const int tid = threadIdx.x;

    #pragma unroll
    for (int i = 0; i < 2; ++i) {
        const int idx = tid + i * 256;  // 0..511
        const int r   = idx >> 6;       // 0..7  (8 k's each)
        const int n   = idx & 63;
        const int qi  = qweight[(size_t)((k0 >> 3) + r) * N_TOT + n0 + n];
        const int zi  = qzeros[g * (N_TOT / 8) + ((n0 + n) >> 3)];
        const float s = scales[g * N_TOT + n0 + n];
        const float zs = (float)(((zi >> ((n & 7) * 4)) & 0xF) + 1) * s;
        bf16x8 v;
        #pragma unroll
        for (int j = 0; j < 8; ++j)
            v[j] = (__bf16)((float)((qi >> (4 * j)) & 0xF) * s - zs);  // (w-z-1)*s
        *(bf16x8*)&T[n * 72 + r * 8] = v;
    }
    __syncthreads();

    const int n = tid >> 2;             // 0..63
    const int c = (tid & 3) * 16;       // 0,16,32,48
    const bf16x8 a = *(const bf16x8*)&T[n * 72 + c];
    const bf16x8 b = *(const bf16x8*)&T[n * 72 + c + 8];
    __bf16* dst = Wt + (size_t)(n0 + n) * K_TOT + k0 + c;
    *(bf16x8*)dst = a;
    *(bf16x8*)(dst + 8) = b;
}

// ------- pass 2: m97-structure bf16 GEMM (B^T), XOR-swizzled LDS -------
#define BM 128
#define BN 128
#define BK 64

__global__ __launch_bounds__(256) void gemm_bt(
    const __bf16* __restrict__ xb,   // [M, K]
    const __bf16* __restrict__ Wt,   // [N, K]
    const float*  __restrict__ bias, // [N]
    float* __restrict__ out)         // [M, N]
{
    __shared__ __align__(16) unsigned short As[BM * BK];  // chunk-swizzled
    __shared__ __align__(16) unsigned short Bs[BN * BK];

    const int tid  = threadIdx.x;
    const int wave = tid >> 6;
    const int lane = tid & 63;
    const int n0 = blockIdx.x * BN;
    const int m0 = blockIdx.y * BM;

    const int wm = (wave >> 1) * 64;
    const int wn = (wave & 1) * 64;
    const int l15  = lane & 15;
    const int quad = lane >> 4;

    f32x4 acc[4][4];
    #pragma unroll
    for (int i = 0; i < 4; ++i)
        #pragma unroll
        for (int j = 0; j < 4; ++j)
            acc[i][j] = (f32x4)0.f;

    for (int kt = 0; kt < K_TOT / BK; ++kt) {
        const int k0 = kt * BK;

        // DMA staging, 16 B/lane. Chunk c holds global k-chunk (c&7)^((c>>3)&7):
        // bank-conflict-free fragment reads, zero LDS-side scatter.
        #pragma unroll
        for (int i = 0; i < 4; ++i) {
            const int c   = tid + i * 256;            // chunk id (16 B each)
            const int row = c >> 3;
            const int kc  = (c & 7) ^ (row & 7);      // XOR swizzle (global side)
            const __bf16* ga = xb + (size_t)(m0 + row) * K_TOT + (k0 + kc * 8);
            __builtin_amdgcn_global_load_lds((as1_void*)ga,
                (as3_void*)&As[(i * 256 + wave * 64) * 8], 16, 0, 0);
            const __bf16* gb = Wt + (size_t)(n0 + row) * K_TOT + (k0 + kc * 8);
            __builtin_amdgcn_global_load_lds((as1_void*)gb,
                (as3_void*)&Bs[(i * 256 + wave * 64) * 8], 16, 0, 0);
        }
        __syncthreads();

        #pragma unroll
        for (int ks = 0; ks < 2; ++ks) {
            bf16x8 av[4], bv[4];
            #pragma unroll
            for (int mt = 0; mt < 4; ++mt) {
                const int r = wm + mt * 16 + l15;
                av[mt] = *(const bf16x8*)&As[r * BK + (((ks * 4 + quad) ^ (r & 7)) << 3)];
            }
            #pragma unroll
            for (int nt = 0; nt < 4; ++nt) {
                const int r = wn + nt * 16 + l15;
                bv[nt] = *(const bf16x8*)&Bs[r * BK + (((ks * 4 + quad) ^ (r & 7)) << 3)];
            }
            #pragma unroll
            for (int mt = 0; mt < 4; ++mt)
                #pragma unroll
                for (int nt = 0; nt < 4; ++nt)
                    acc[mt][nt] = __builtin_amdgcn_mfma_f32_16x16x32_bf16(
                        av[mt], bv[nt], acc[mt][nt], 0, 0, 0);
        }
        __syncthreads();
    }

    // epilogue: C/D layout col=lane&15, row=quad*4+reg (m89/m91-verified)
    #pragma unroll
    for (int nt = 0; nt < 4; ++nt) {
        const int col = n0 + wn + nt * 16 + l15;
        const float bv = bias[col];
        #pragma unroll
        for (int mt = 0; mt < 4; ++mt) {
            const int rowb = m0 + wm + mt * 16 + quad * 4;
            #pragma unroll
            for (int i = 0; i < 4; ++i)
                out[(size_t)(rowb + i) * N_TOT + col] = acc[mt][nt][i] + bv;
        }
    }
}

// ---------------- fallback: round-4 fused kernel (proven correct) ----------------
#define FBM 256
#define FBN 128
#define FBKP 72

__global__ __launch_bounds__(256, 2) void gptq_gemm_fused(
    const float* __restrict__ x, const int* __restrict__ qweight,
    const int* __restrict__ qzeros, const float* __restrict__ scales,
    const int* __restrict__ g_idx, const float* __restrict__ bias,
    float* __restrict__ out)
{
    __shared__ __align__(16) unsigned short As[FBM * FBKP];
    __shared__ __align__(16) unsigned short Bt[FBN * FBKP];

    const int tid  = threadIdx.x;
    const int wave = tid >> 6;
    const int lane = tid & 63;
    const int n0 = blockIdx.x * FBN;
    const int m0 = blockIdx.y * FBM;
    const int wm = (wave >> 1) * 64;
    const int wn = (wave & 1) * 64;
    const int l15  = lane & 15;
    const int quad = lane >> 4;

    f32x4 acc[2][4][4];
    #pragma unroll
    for (int mi = 0; mi < 2; ++mi)
        #pragma unroll
        for (int i = 0; i < 4; ++i)
            #pragma unroll
            for (int j = 0; j < 4; ++j)
                acc[mi][i][j] = (f32x4)0.f;

    const int nb  = tid & 31;
    const int r   = tid >> 5;
    const int zsh = (nb & 7) * 4;

    for (int kt = 0; kt < K_TOT / 64; ++kt) {
        const int k0 = kt * 64;
        #pragma unroll
        for (int i = 0; i < 8; ++i) {
            const int c   = tid + i * 256;
            const int row = c >> 3;
            const int cb  = (c & 7) << 3;
            const float* xp = x + (size_t)(m0 + row) * K_TOT + (k0 + cb);
            const float4 f0 = *(const float4*)xp;
            const float4 f1 = *(const float4*)(xp + 4);
            bf16x8 v;
            v[0]=(__bf16)f0.x; v[1]=(__bf16)f0.y; v[2]=(__bf16)f0.z; v[3]=(__bf16)f0.w;
            v[4]=(__bf16)f1.x; v[5]=(__bf16)f1.y; v[6]=(__bf16)f1.z; v[7]=(__bf16)f1.w;
            *(bf16x8*)&As[row * FBKP + cb] = v;
        }
        const int g    = g_idx[k0];
        const int qrow = (k0 >> 3) + r;
        #pragma unroll
        for (int dn = 0; dn < 4; ++dn) {
            const int n  = nb + dn * 32;
            const int qi = qweight[(size_t)qrow * N_TOT + (n0 + n)];
            const int zi = qzeros[g * (N_TOT / 8) + ((n0 + n) >> 3)];
            const float s = scales[g * N_TOT + (n0 + n)];
            const float zs = (float)(((zi >> zsh) & 0xF) + 1) * s;
            bf16x8 v;
            #pragma unroll
            for (int j = 0; j < 8; ++j)
                v[j] = (__bf16)((float)((qi >> (4 * j)) & 0xF) * s - zs);
            *(bf16x8*)&Bt[n * FBKP + r * 8] = v;
        }
        __syncthreads();
        #pragma unroll
        for (int ks = 0; ks < 2; ++ks) {
            bf16x8 bv[4];
            #pragma unroll
            for (int nt = 0; nt < 4; ++nt)
                bv[nt] = *(const bf16x8*)&Bt[(wn + nt * 16 + l15) * FBKP + ks * 32 + quad * 8];
            #pragma unroll
            for (int mi = 0; mi < 2; ++mi) {
                bf16x8 av[4];
                #pragma unroll
                for (int mt = 0; mt < 4; ++mt)
                    av[mt] = *(const bf16x8*)&As[(mi * 128 + wm + mt * 16 + l15) * FBKP + ks * 32 + quad * 8];
                #pragma unroll
                for (int mt = 0; mt < 4; ++mt)
                    #pragma unroll
                    for (int nt = 0; nt < 4; ++nt)
                        acc[mi][mt][nt] = __builtin_amdgcn_mfma_f32_16x16x32_bf16(
                            av[mt], bv[nt], acc[mi][mt][nt], 0, 0, 0);
            }
        }
        __syncthreads();
    }
    #pragma unroll
    for (int mi = 0; mi < 2; ++mi)
        #pragma unroll
        for (int nt = 0; nt < 4; ++nt) {
            const int col = n0 + wn + nt * 16 + l15;
            const float bv = bias[col];
            #pragma unroll
            for (int mt = 0; mt < 4; ++mt) {
                const int rowb = m0 + mi * 128 + wm + mt * 16 + quad * 4;
                #pragma unroll
                for (int i = 0; i < 4; ++i)
                    out[(size_t)(rowb + i) * N_TOT + col] = acc[mi][mt][nt][i] + bv;
            }
        }
}

extern "C" void kernel_launch(void* const* d_in, const int* in_sizes, int n_in,
                              void* d_out, int out_size, void* d_ws, size_t ws_size,
                              hipStream_t stream) {
    const float* x  = (const float*)d_in[0];
    const int*   qw = (const int*)d_in[1];
    const int*   qz = (const int*)d_in[2];
    const float* sc = (const float*)d_in[3];
    const int*   gi = (const int*)d_in[4];
    const float* bs = (const float*)d_in[5];
    float* out = (float*)d_out;

    const size_t xb_bytes = (size_t)M_TOT * K_TOT * 2;   // 67,108,864
    const size_t wt_bytes = (size_t)N_TOT * K_TOT * 2;   // 33,554,432

    if (ws_size >= xb_bytes + wt_bytes) {
        __bf16* xb = (__bf16*)d_ws;
        __bf16* Wt = (__bf16*)((char*)d_ws + xb_bytes);
        cast_x<<<dim3((M_TOT * K_TOT) / (256 * 8)), dim3(256), 0, stream>>>(x, xb);
        dequant_w<<<dim3(K_TOT / 64, N_TOT / 64), dim3(256), 0, stream>>>(qw, qz, sc, gi, Wt);
        gemm_bt<<<dim3(N_TOT / BN, M_TOT / BM), dim3(256), 0, stream>>>(xb, Wt, bs, out);
    } else {
        gptq_gemm_fused<<<dim3(N_TOT / FBN, M_TOT / FBM), dim3(256), 0, stream>>>(
            x, qw, qz, sc, gi, bs, out);
    }
}